// Round 2
// baseline (1191.312 us; speedup 1.0000x reference)
//
#include <hip/hip_runtime.h>

typedef unsigned short u16;
typedef __bf16 bf16x8 __attribute__((ext_vector_type(8)));
typedef float floatx4 __attribute__((ext_vector_type(4)));

#define NE 800000
#define NN 50000
#define CHUNKS 32
#define CHUNK (NE / CHUNKS)   // 25000
#define WIN 25000             // histogram window per segment (2 windows per array)
#define NBKT 32               // src-range buckets for the sweep
#define DPW 8                 // dsts per wave in sweep kernels

__device__ __forceinline__ float b2f(unsigned u) { return __uint_as_float(u << 16); }
__device__ __forceinline__ u16 f2b(float f) {
  unsigned x = __float_as_uint(f);
  x += 0x7fffu + ((x >> 16) & 1u);
  return (u16)(x >> 16);
}
__device__ __forceinline__ int clampi(int s) {
  return (s < 0) ? 0 : (s > NN - 1 ? NN - 1 : s);
}

// ---------------- bucket sort of edges by src range (32 buckets) ----------------
// Makes per-dst CSR lists ~ascending in src (bucket granularity) so that the
// sweep SpMM kernels walk a global moving window over the feature matrix.
__global__ __launch_bounds__(256) void k_bcount(const int* __restrict__ s0,
                                                const int* __restrict__ s1,
                                                const int* __restrict__ s2,
                                                unsigned* __restrict__ bcnt) {
  __shared__ unsigned h[NBKT];
  int c = blockIdx.x, r = blockIdx.y, t = threadIdx.x;
  if (t < NBKT) h[t] = 0;
  __syncthreads();
  const int* s = (r == 0) ? s0 : (r == 1) ? s1 : s2;
  int st = c * CHUNK, en = st + CHUNK;
  for (int e = st + t; e < en; e += 256) {
    unsigned b = (unsigned)(clampi(s[e]) * NBKT) / (unsigned)NN;
    atomicAdd(&h[b], 1u);
  }
  __syncthreads();
  if (t < NBKT) bcnt[(r * CHUNKS + c) * NBKT + t] = h[t];
}

// bbase[r][c][b] = global start slot for (chunk c, bucket b) of relation r,
// bucket-major ordering: all of bucket 0, then bucket 1, ...
__global__ __launch_bounds__(128) void k_bscan(const unsigned* __restrict__ bcnt,
                                               unsigned* __restrict__ bbase) {
  __shared__ unsigned tot[96];
  int t = threadIdx.x;
  if (t < 96) {
    int r = t / NBKT, b = t % NBKT;
    unsigned run = 0;
    for (int c = 0; c < CHUNKS; ++c) {
      bbase[(r * CHUNKS + c) * NBKT + b] = run;
      run += bcnt[(r * CHUNKS + c) * NBKT + b];
    }
    tot[t] = run;
  }
  __syncthreads();
  if (t < 96) {
    int r = t / NBKT, b = t % NBKT;
    unsigned base = 0;
    for (int b2 = 0; b2 < b; ++b2) base += tot[r * NBKT + b2];
    for (int c = 0; c < CHUNKS; ++c) bbase[(r * CHUNKS + c) * NBKT + b] += base;
  }
}

__global__ __launch_bounds__(256) void k_bscatter(
    const int* __restrict__ s0, const int* __restrict__ d0_,
    const int* __restrict__ s1, const int* __restrict__ d1_,
    const int* __restrict__ s2, const int* __restrict__ d2_,
    const unsigned* __restrict__ bbase, int* __restrict__ edgS) {
  __shared__ unsigned rk[NBKT];
  int c = blockIdx.x, r = blockIdx.y, t = threadIdx.x;
  if (t < NBKT) rk[t] = 0;
  __syncthreads();
  const int* s = (r == 0) ? s0 : (r == 1) ? s1 : s2;
  const int* d = (r == 0) ? d0_ : (r == 1) ? d1_ : d2_;
  int* srcS = edgS + r * NE;
  int* dstS = edgS + 3 * NE + r * NE;
  const unsigned* bb = bbase + (r * CHUNKS + c) * NBKT;
  int st = c * CHUNK, en = st + CHUNK;
  for (int e = st + t; e < en; e += 256) {
    int sv = clampi(s[e]);
    unsigned b = (unsigned)(sv * NBKT) / (unsigned)NN;
    unsigned pos = atomicAdd(&rk[b], 1u);
    unsigned slot = bb[b] + pos;
    srcS[slot] = sv;
    dstS[slot] = d[e];
  }
}

// ---------------- histogram degrees (LDS, atomic-free in HBM) ----------------
// segment g in [0,12): array a=g>>1, window r=g&1 covering idx in [r*WIN,(r+1)*WIN)
// arrays: 0=dstF 1=dstRB 2=dstR 3=srcF 4=srcR 5=srcRB  (matches DI layout below)
__global__ __launch_bounds__(256) void k_hist(
    const int* __restrict__ dF, const int* __restrict__ dRB, const int* __restrict__ dR,
    const int* __restrict__ sF, const int* __restrict__ sR, const int* __restrict__ sRB,
    u16* __restrict__ partial) {
  __shared__ unsigned h[WIN / 2];          // packed u16 pairs, 50 KB
  int c = blockIdx.x, g = blockIdx.y, t = threadIdx.x;
  int a = g >> 1, lo = (g & 1) * WIN;
  for (int i = t; i < WIN / 2; i += 256) h[i] = 0;
  __syncthreads();
  const int* idx = (a == 0) ? dF : (a == 1) ? dRB : (a == 2) ? dR
                 : (a == 3) ? sF : (a == 4) ? sR : sRB;
  int st = c * CHUNK, en = st + CHUNK;
  for (int e = st + t; e < en; e += 256) {
    unsigned u = (unsigned)(idx[e] - lo);
    if (u < (unsigned)WIN) atomicAdd(&h[u >> 1], 1u << ((u & 1) * 16));
  }
  __syncthreads();
  unsigned* po = (unsigned*)(partial + ((size_t)g * CHUNKS + c) * WIN);
  for (int i = t; i < WIN / 2; i += 256) po[i] = h[i];
}

// partials -> DI counts; byproduct: exclusive per-chunk cumsum for relations (g<6)
__global__ __launch_bounds__(256) void k_hreduce(const u16* __restrict__ partial,
                                                 u16* __restrict__ chunkcum,
                                                 int* __restrict__ DI) {
  int i = blockIdx.x * 256 + threadIdx.x;
  int g = blockIdx.y;
  if (i >= WIN) return;
  const u16* p = partial + (size_t)g * CHUNKS * WIN + i;
  u16* cc = chunkcum + (size_t)g * CHUNKS * WIN + i;   // only meaningful for g<6
  int run = 0;
#pragma unroll
  for (int c = 0; c < CHUNKS; ++c) {
    if (g < 6) cc[(size_t)c * WIN] = (u16)run;
    run += p[(size_t)c * WIN];
  }
  int a = g >> 1, r = g & 1;
  DI[a * NN + r * WIN + i] = run;
}

// parallel exclusive scan over 150000 counts -> offs[0..150000]
__global__ __launch_bounds__(1024) void k_scan1(const int* __restrict__ cnt,
                                                int* __restrict__ offs,
                                                int* __restrict__ partials) {
  __shared__ int tmp[1024];
  int t = threadIdx.x, i = blockIdx.x * 1024 + t;
  int c = (i < 150000) ? cnt[i] : 0;
  tmp[t] = c; __syncthreads();
  for (int off = 1; off < 1024; off <<= 1) {
    int v = (t >= off) ? tmp[t - off] : 0;
    __syncthreads();
    tmp[t] += v;
    __syncthreads();
  }
  if (i <= 150000) offs[i] = tmp[t] - c;
  if (t == 1023) partials[blockIdx.x] = tmp[1023];
}

__global__ __launch_bounds__(256) void k_scan2(int* __restrict__ partials) {
  __shared__ int tmp[256];
  int t = threadIdx.x;
  int c = (t < 147) ? partials[t] : 0;
  tmp[t] = c; __syncthreads();
  for (int off = 1; off < 256; off <<= 1) {
    int v = (t >= off) ? tmp[t - off] : 0;
    __syncthreads();
    tmp[t] += v;
    __syncthreads();
  }
  if (t < 147) partials[t] = tmp[t] - c;
}

__global__ __launch_bounds__(1024) void k_scan3(int* __restrict__ offs,
                                                const int* __restrict__ partials) {
  int i = blockIdx.x * 1024 + threadIdx.x;
  if (i <= 150000) offs[i] += partials[blockIdx.x];
}

__global__ void k_rsq(int* __restrict__ DI, int n) {
  int i = blockIdx.x * 256 + threadIdx.x;
  if (i < n) {
    float v = (float)DI[i];
    ((float*)DI)[i] = rsqrtf(fmaxf(v, 1.f));
  }
}

// CSR scatter, atomic-free: slot = offs[dst] + chunkcum[dst] + LDS-rank
__global__ __launch_bounds__(256) void k_scatlds(
    const int* __restrict__ sF, const int* __restrict__ dF,
    const int* __restrict__ sRB, const int* __restrict__ dRB,
    const int* __restrict__ sR, const int* __restrict__ dR,
    const int* __restrict__ offs, const u16* __restrict__ chunkcum,
    int* __restrict__ csr) {
  __shared__ unsigned h[WIN / 2];          // rank counters, 50 KB
  int c = blockIdx.x, g = blockIdx.y, t = threadIdx.x;
  int a = g >> 1, lo = (g & 1) * WIN;
  for (int i = t; i < WIN / 2; i += 256) h[i] = 0;
  __syncthreads();
  const int* s = (a == 0) ? sF : (a == 1) ? sRB : sR;
  const int* d = (a == 0) ? dF : (a == 1) ? dRB : dR;
  int base = a * NN;
  const u16* cc = chunkcum + ((size_t)g * CHUNKS + c) * WIN;
  int st = c * CHUNK, en = st + CHUNK;
  for (int e = st + t; e < en; e += 256) {
    int dd = d[e];
    unsigned u = (unsigned)(dd - lo);
    if (u < (unsigned)WIN) {
      unsigned sh = (u & 1) * 16;
      unsigned old = atomicAdd(&h[u >> 1], 1u << sh);
      int r = (int)((old >> sh) & 0xffffu);
      csr[offs[base + dd] + (int)cc[u] + r] = s[e];
    }
  }
}

// 6 weight transposes fused: dst[n*256+k] = f2b(src[k*N+n]), K=256 rows
__global__ void k_tpose6(const float* __restrict__ W1f, const float* __restrict__ W1rt,
                         const float* __restrict__ W1rb, const float* __restrict__ W2f,
                         const float* __restrict__ W2rt, const float* __restrict__ W2rb,
                         u16* __restrict__ Bt1u, u16* __restrict__ Bt1i,
                         u16* __restrict__ Bt2u, u16* __restrict__ Bt2i) {
  int a = blockIdx.y;
  const float* src; u16* dst; int N;
  switch (a) {
    case 0: src = W1f;  dst = Bt1u;         N = 256; break;
    case 1: src = W1rt; dst = Bt1u + 65536; N = 256; break;
    case 2: src = W1rb; dst = Bt1i;         N = 256; break;
    case 3: src = W2f;  dst = Bt2u;         N = 128; break;
    case 4: src = W2rt; dst = Bt2u + 32768; N = 128; break;
    default: src = W2rb; dst = Bt2i;        N = 128; break;
  }
  int i = blockIdx.x * 256 + threadIdx.x;
  if (i < 256 * N) {
    int n = i >> 8, k = i & 255;
    dst[i] = f2b(src[(size_t)k * N + n]);
  }
}

// ---------------- GEMM: C[M,Ntot] = A[M,256] @ Bt[Ntot,256]^T, epilogue row-scale ----------------
template <bool AF32>
__global__ __launch_bounds__(256) void k_gemm(
    const void* __restrict__ A, const u16* __restrict__ Bt, u16* __restrict__ C,
    int M, int Ntot, const float* __restrict__ rs0, const float* __restrict__ rs1, int splitN) {
  __shared__ alignas(16) u16 As[128 * 64];
  __shared__ alignas(16) u16 Bs[128 * 64];
  const int tid = threadIdx.x;
  const int mBase = blockIdx.x * 128;
  const int nBase = blockIdx.y * 128;
  const int w = tid >> 6, lane = tid & 63;
  const int wm = w & 1, wn = w >> 1;
  const int lr = lane & 15, quad = lane >> 4;
  floatx4 acc[4][4] = {};
  for (int kb = 0; kb < 256; kb += 64) {
    uint4 va[4], vb[4];
#pragma unroll
    for (int c = 0; c < 4; ++c) {
      int idx = c * 256 + tid;
      int row = idx >> 3;
      int col8 = (idx & 7) * 8;
      int gr = mBase + row; if (gr > M - 1) gr = M - 1;
      if constexpr (AF32) {
        const float* ap = (const float*)A + (size_t)gr * 256 + kb + col8;
        float4 f0 = *(const float4*)ap;
        float4 f1 = *(const float4*)(ap + 4);
        va[c] = make_uint4(
            (unsigned)f2b(f0.x) | ((unsigned)f2b(f0.y) << 16),
            (unsigned)f2b(f0.z) | ((unsigned)f2b(f0.w) << 16),
            (unsigned)f2b(f1.x) | ((unsigned)f2b(f1.y) << 16),
            (unsigned)f2b(f1.z) | ((unsigned)f2b(f1.w) << 16));
      } else {
        va[c] = *(const uint4*)((const u16*)A + (size_t)gr * 256 + kb + col8);
      }
      vb[c] = *(const uint4*)(Bt + (size_t)(nBase + row) * 256 + kb + col8);
    }
#pragma unroll
    for (int c = 0; c < 4; ++c) {
      int idx = c * 256 + tid;
      *(uint4*)(&As[idx * 8]) = va[c];
      *(uint4*)(&Bs[idx * 8]) = vb[c];
    }
    __syncthreads();
#pragma unroll
    for (int ks = 0; ks < 2; ++ks) {
      bf16x8 fa[4], fb[4];
#pragma unroll
      for (int m = 0; m < 4; ++m)
        fa[m] = *(const bf16x8*)(&As[(wm * 64 + m * 16 + lr) * 64 + ks * 32 + quad * 8]);
#pragma unroll
      for (int n = 0; n < 4; ++n)
        fb[n] = *(const bf16x8*)(&Bs[(wn * 64 + n * 16 + lr) * 64 + ks * 32 + quad * 8]);
#pragma unroll
      for (int m = 0; m < 4; ++m)
#pragma unroll
        for (int n = 0; n < 4; ++n)
          acc[m][n] = __builtin_amdgcn_mfma_f32_16x16x32_bf16(fa[m], fb[n], acc[m][n], 0, 0, 0);
    }
    __syncthreads();
  }
#pragma unroll
  for (int n = 0; n < 4; ++n) {
    int cg = nBase + wn * 64 + n * 16 + lr;
    const float* rs = (cg < splitN) ? rs0 : rs1;
#pragma unroll
    for (int m = 0; m < 4; ++m) {
      int rb_ = mBase + wm * 64 + m * 16 + quad * 4;
#pragma unroll
      for (int r = 0; r < 4; ++r) {
        int rg = rb_ + r;
        if (rg < M) C[(size_t)rg * Ntot + cg] = f2b(acc[m][n][r] * rs[rg]);
      }
    }
  }
}

// ---------------- SpMM sweep (CSR by dst, lists bucket-sorted by src) ----------------
// Each wave owns DPW consecutive dsts; all waves advance through src buckets in
// a global phase loop, so the instantaneous gather window is ~2-3 buckets
// (~3-5 MB) -> L2/LLC resident. Reuse distance drops ~16x.

template <int VEC>
__device__ __forceinline__ uint2 ldrow(const u16* __restrict__ p) {
  uint2 r;
  if constexpr (VEC == 4) {
    r = *(const uint2*)p;
  } else {
    r.x = *(const unsigned*)p;
    r.y = 0u;
  }
  return r;
}

template <int VEC>
__device__ __forceinline__ void accum(float* acc, uint2 v) {
  acc[0] += b2f(v.x & 0xffffu);
  acc[1] += b2f(v.x >> 16);
  if constexpr (VEC == 4) {
    acc[2] += b2f(v.y & 0xffffu);
    acc[3] += b2f(v.y >> 16);
  }
}

template <int VEC, bool RELU, bool OUT32>
__global__ __launch_bounds__(64) void k_sweep2(
    const u16* __restrict__ fA, int sA, int oA,
    const u16* __restrict__ fB, int sB, int oB,
    const int* __restrict__ csr, const int* __restrict__ offs, int baseA, int baseB,
    const float* __restrict__ rsA, const float* __restrict__ rsB,
    const float* __restrict__ bA, const float* __restrict__ bB,
    void* __restrict__ outv, size_t outBase, int sOut) {
  int lane = threadIdx.x;
  int d0 = blockIdx.x * DPW;
  int eA[DPW], nA[DPW], eB[DPW], nB[DPW];
  int sAv[DPW], sBv[DPW];                  // next src value (clamped) or INT_MAX
  float aA[DPW][VEC] = {}, aB[DPW][VEC] = {};
#pragma unroll
  for (int i = 0; i < DPW; ++i) {
    int d = d0 + i;
    int dd = (d < NN) ? d : NN - 1;
    bool ok = d < NN;
    eA[i] = offs[baseA + dd]; nA[i] = ok ? offs[baseA + dd + 1] : eA[i];
    eB[i] = offs[baseB + dd]; nB[i] = ok ? offs[baseB + dd + 1] : eB[i];
    sAv[i] = (eA[i] < nA[i]) ? clampi(csr[eA[i]]) : 0x7fffffff;
    sBv[i] = (eB[i] < nB[i]) ? clampi(csr[eB[i]]) : 0x7fffffff;
  }
  const u16* pA = fA + oA + lane * VEC;
  const u16* pB = fB + oB + lane * VEC;
  for (int b = 0; b < NBKT; ++b) {
    int lim = ((b + 1) * NN + NBKT - 1) / NBKT;
#pragma unroll
    for (int i = 0; i < DPW; ++i) {
      while (sAv[i] < lim) {
        accum<VEC>(aA[i], ldrow<VEC>(pA + (size_t)sAv[i] * sA));
        ++eA[i];
        sAv[i] = (eA[i] < nA[i]) ? clampi(csr[eA[i]]) : 0x7fffffff;
      }
      while (sBv[i] < lim) {
        accum<VEC>(aB[i], ldrow<VEC>(pB + (size_t)sBv[i] * sB));
        ++eB[i];
        sBv[i] = (eB[i] < nB[i]) ? clampi(csr[eB[i]]) : 0x7fffffff;
      }
    }
  }
  float bva[VEC], bvb[VEC];
#pragma unroll
  for (int v = 0; v < VEC; ++v) { bva[v] = bA[lane * VEC + v]; bvb[v] = bB[lane * VEC + v]; }
#pragma unroll
  for (int i = 0; i < DPW; ++i) {
    int d = d0 + i;
    if (d >= NN) break;
    float ra = rsA[d], rb = rsB[d];
    size_t o = outBase + (size_t)d * sOut + lane * VEC;
#pragma unroll
    for (int v = 0; v < VEC; ++v) {
      float x = 0.5f * (aA[i][v] * ra + bva[v] + aB[i][v] * rb + bvb[v]);
      if (RELU) x = fmaxf(x, 0.f);
      if (OUT32) ((float*)outv)[o + v] = x;
      else       ((u16*)outv)[o + v] = f2b(x);
    }
  }
}

template <int VEC, bool RELU, bool OUT32>
__global__ __launch_bounds__(64) void k_sweep1(
    const u16* __restrict__ fA, int sA, int oA,
    const int* __restrict__ csr, const int* __restrict__ offs, int baseA,
    const float* __restrict__ rsA, const float* __restrict__ bA,
    void* __restrict__ outv, size_t outBase, int sOut) {
  int lane = threadIdx.x;
  int d0 = blockIdx.x * DPW;
  int eA[DPW], nA[DPW], sAv[DPW];
  float aA[DPW][VEC] = {};
#pragma unroll
  for (int i = 0; i < DPW; ++i) {
    int d = d0 + i;
    int dd = (d < NN) ? d : NN - 1;
    bool ok = d < NN;
    eA[i] = offs[baseA + dd]; nA[i] = ok ? offs[baseA + dd + 1] : eA[i];
    sAv[i] = (eA[i] < nA[i]) ? clampi(csr[eA[i]]) : 0x7fffffff;
  }
  const u16* pA = fA + oA + lane * VEC;
  for (int b = 0; b < NBKT; ++b) {
    int lim = ((b + 1) * NN + NBKT - 1) / NBKT;
#pragma unroll
    for (int i = 0; i < DPW; ++i) {
      while (sAv[i] < lim) {
        accum<VEC>(aA[i], ldrow<VEC>(pA + (size_t)sAv[i] * sA));
        ++eA[i];
        sAv[i] = (eA[i] < nA[i]) ? clampi(csr[eA[i]]) : 0x7fffffff;
      }
    }
  }
  float bva[VEC];
#pragma unroll
  for (int v = 0; v < VEC; ++v) bva[v] = bA[lane * VEC + v];
#pragma unroll
  for (int i = 0; i < DPW; ++i) {
    int d = d0 + i;
    if (d >= NN) break;
    float ra = rsA[d];
    size_t o = outBase + (size_t)d * sOut + lane * VEC;
#pragma unroll
    for (int v = 0; v < VEC; ++v) {
      float x = aA[i][v] * ra + bva[v];
      if (RELU) x = fmaxf(x, 0.f);
      if (OUT32) ((float*)outv)[o + v] = x;
      else       ((u16*)outv)[o + v] = f2b(x);
    }
  }
}

extern "C" void kernel_launch(void* const* d_in, const int* in_sizes, int n_in,
                              void* d_out, int out_size, void* d_ws, size_t ws_size,
                              hipStream_t stream) {
  (void)in_sizes; (void)n_in; (void)out_size;
  const float* x_user = (const float*)d_in[0];
  const float* x_item = (const float*)d_in[1];
  const float* W1f  = (const float*)d_in[2];  const float* b1f  = (const float*)d_in[3];
  const float* W1rt = (const float*)d_in[4];  const float* b1rt = (const float*)d_in[5];
  const float* W1rb = (const float*)d_in[6];  const float* b1rb = (const float*)d_in[7];
  const float* W2f  = (const float*)d_in[8];  const float* b2fo = (const float*)d_in[9];
  const float* W2rt = (const float*)d_in[10]; const float* b2rt = (const float*)d_in[11];
  const float* W2rb = (const float*)d_in[12]; const float* b2rb = (const float*)d_in[13];
  const int* srcF  = (const int*)d_in[14]; const int* dstF  = (const int*)d_in[15];
  const int* srcR  = (const int*)d_in[16]; const int* dstR  = (const int*)d_in[17];
  const int* srcRB = (const int*)d_in[18]; const int* dstRB = (const int*)d_in[19];

  // ---- workspace layout (bytes) ----
  // DI/R   : [0, 1200000)           300000 i32 -> f32 in place
  // offs   : [1800064, 2400068)     150001 i32
  // csr    : [2400128, 12000128)    2400000 i32  (first 588 B double as scan partials)
  // Bt1u/Bt1i/Bt2u/Bt2i bf16        [12000128, 12589952)
  // featA  : [12589952, 63789952)   [50000,512] bf16
  //          scratch (pre-GEMM): hpart u16 12*32*25000 @featA+0 (19.2MB),
  //                              chunkcum u16 6*32*25000 @featA+19.2MB (9.6MB),
  //                              edgS i32 6*800000 @featA+28.8MB (19.2MB),
  //                              bcnt/bbase u32 @ws+60589952 (24KB)
  // featB  : [63789952, 89389952)   [50000,256]
  // h_u    : [89389952, 114989952)  [50000,256]
  if (ws_size < 114989952u) return;

  char* ws = (char*)d_ws;
  int*   DI     = (int*)ws;
  float* R      = (float*)ws;
  int*   offs   = (int*)(ws + 1800064);
  int*   csr    = (int*)(ws + 2400128);
  int*   partials = csr;                    // scan scratch, free until k_scatlds
  u16*   Bt1u   = (u16*)(ws + 12000128);
  u16*   Bt1i   = (u16*)(ws + 12262272);
  u16*   Bt2u   = (u16*)(ws + 12393344);
  u16*   Bt2i   = (u16*)(ws + 12524416);
  u16*   featA  = (u16*)(ws + 12589952);
  u16*   featB  = (u16*)(ws + 63789952);
  u16*   h_u    = (u16*)(ws + 89389952);
  u16*   h_i    = featB;
  u16*   feat2rb = featA + (size_t)50000 * 256;
  u16*   hpart  = featA;                    // 12*32*25000 u16, dead before GEMM1
  u16*   chunkcum = featA + (size_t)12 * CHUNKS * WIN;  // 6*32*25000 u16
  int*   edgS   = (int*)(ws + 41389952);    // 6*800000 i32 bucket-sorted edges
  unsigned* bcnt  = (unsigned*)(ws + 60589952);
  unsigned* bbase = bcnt + 3 * CHUNKS * NBKT;

  // bucket-sort edges by src range (per relation): srcS[r]=edgS+r*NE, dstS[r]=edgS+3*NE+r*NE
  k_bcount<<<dim3(CHUNKS, 3), 256, 0, stream>>>(srcF, srcRB, srcR, bcnt);
  k_bscan<<<1, 128, 0, stream>>>(bcnt, bbase);
  k_bscatter<<<dim3(CHUNKS, 3), 256, 0, stream>>>(srcF, dstF, srcRB, dstRB, srcR, dstR,
                                                  bbase, edgS);
  int* srcS_F  = edgS;            int* dstS_F  = edgS + 3 * NE;
  int* srcS_RB = edgS + NE;       int* dstS_RB = edgS + 4 * NE;
  int* srcS_R  = edgS + 2 * NE;   int* dstS_R  = edgS + 5 * NE;

  k_hist<<<dim3(CHUNKS, 12), 256, 0, stream>>>(dstS_F, dstS_RB, dstS_R, srcF, srcR, srcRB, hpart);
  k_hreduce<<<dim3(98, 12), 256, 0, stream>>>(hpart, chunkcum, DI);
  k_scan1<<<147, 1024, 0, stream>>>(DI, offs, partials);
  k_scan2<<<1, 256, 0, stream>>>(partials);
  k_scan3<<<147, 1024, 0, stream>>>(offs, partials);
  k_rsq<<<(300000 + 255) / 256, 256, 0, stream>>>(DI, 300000);
  k_scatlds<<<dim3(CHUNKS, 6), 256, 0, stream>>>(srcS_F, dstS_F, srcS_RB, dstS_RB,
                                                 srcS_R, dstS_R, offs, chunkcum, csr);
  k_tpose6<<<dim3(256, 6), 256, 0, stream>>>(W1f, W1rt, W1rb, W2f, W2rt, W2rb,
                                             Bt1u, Bt1i, Bt2u, Bt2i);

  const int SWG = (NN + DPW - 1) / DPW;     // 6250 blocks of 1 wave

  // layer 1 GEMMs (rsqrt(out_deg) row scale commutes with @W; applied in epilogue)
  k_gemm<true><<<dim3(391, 4), 256, 0, stream>>>(x_user, Bt1u, featA, 50000, 512,
                                                 R + 150000, R + 200000, 256);
  k_gemm<true><<<dim3(391, 2), 256, 0, stream>>>(x_item, Bt1i, featB, 50000, 256,
                                                 R + 250000, R + 250000, 256);
  // layer 1 aggregation (bf16 stores into ws)
  k_sweep2<4, true, false><<<SWG, 64, 0, stream>>>(featA, 512, 0, featB, 256, 0,
                                                   csr, offs, 0, 50000,
                                                   R, R + 50000, b1f, b1rb, h_u, 0, 256);
  k_sweep1<4, true, false><<<SWG, 64, 0, stream>>>(featA, 512, 256, csr, offs, 100000,
                                                   R + 100000, b1rt, h_i, 0, 256);
  // layer 2 GEMMs (A = bf16 ws buffers)
  k_gemm<false><<<dim3(391, 2), 256, 0, stream>>>(h_u, Bt2u, featA, 50000, 256,
                                                  R + 150000, R + 200000, 128);
  k_gemm<false><<<dim3(391, 1), 256, 0, stream>>>(h_i, Bt2i, feat2rb, 50000, 128,
                                                  R + 250000, R + 250000, 128);
  // layer 2 aggregation -> d_out (fp32)
  k_sweep2<2, false, true><<<SWG, 64, 0, stream>>>(featA, 256, 0, feat2rb, 128, 0,
                                                   csr, offs, 0, 50000,
                                                   R, R + 50000, b2fo, b2rb, d_out, 0, 128);
  k_sweep1<2, false, true><<<SWG, 64, 0, stream>>>(featA, 256, 128, csr, offs, 100000,
                                                   R + 100000, b2rt, d_out,
                                                   (size_t)50000 * 128, 128);
}